// Round 11
// baseline (144.022 us; speedup 1.0000x reference)
//
#include <hip/hip_runtime.h>

#define BB 8
#define NN 1024
#define CC 128
#define GG 4
#define LL 8
#define GD 64

typedef __attribute__((ext_vector_type(8))) short short8;
typedef __attribute__((ext_vector_type(4))) short short4v;
typedef __attribute__((ext_vector_type(4))) float floatx4;

__device__ __forceinline__ short f2b(float f) {
  union { float f; unsigned u; } c; c.f = f;
  unsigned u = c.u;
  return (short)((u + 0x7FFFu + ((u >> 16) & 1u)) >> 16);   // RNE fp32->bf16
}
__device__ __forceinline__ float b2f(short s) {
  union { unsigned u; float f; } c; c.u = ((unsigned)(unsigned short)s) << 16;
  return c.f;
}
__device__ __forceinline__ void split2(float v, short& hi, short& lo) {
  short h = f2b(v);
  hi = h;
  lo = f2b(v - b2f(h));
}

// packed fp32x2 -> bf16x2 (dword: low=a, high=b)
#if __has_builtin(__builtin_amdgcn_cvt_pk_bf16_f32)
__device__ __forceinline__ unsigned pk2(float a, float b) {
  auto r = __builtin_amdgcn_cvt_pk_bf16_f32(a, b);
  unsigned u; __builtin_memcpy(&u, &r, 4); return u;
}
#else
__device__ __forceinline__ unsigned pk2(float a, float b) {
  return (unsigned)(unsigned short)f2b(a) | ((unsigned)(unsigned short)f2b(b) << 16);
}
#endif

#if __has_builtin(__builtin_amdgcn_exp2f)
#define EXP2(x) __builtin_amdgcn_exp2f(x)
#else
#define EXP2(x) exp2f(x)
#endif

// ---------------- Kernel A: projections, W hi/lo-split staged in LDS ------
#define BHP 136   // shorts per W row in LDS; 68 dwords, 68%32=4 -> 2-way free

__global__ __launch_bounds__(256) void proj_kernel(
    const float* __restrict__ x, const float* __restrict__ Wq,
    const float* __restrict__ Wk, const float* __restrict__ Wv,
    short* __restrict__ qb, short* __restrict__ kb, short* __restrict__ vtb)
{
  __shared__ short bh[64 * BHP];   // 17408 B
  __shared__ short bl[64 * BHP];   // 17408 B
  const int t = threadIdx.x;
  const int nt = blockIdx.x & 3;
  const int mt = blockIdx.x >> 2;
  const int w = t >> 6;
  const int lane = t & 63;
  const int ln = lane & 15;
  const int hq = lane >> 4;
  const int arow = mt * 64 + w * 16 + ln;

  const float* wbase = (nt == 0) ? Wq : (nt == 1) ? Wk : (Wv + (nt - 2) * 64 * 128);

  // stage + split W: thread -> row t>>2, cols (t&3)*32..+31
  {
    int r = t >> 2, c0 = (t & 3) * 32;
    const float* src = wbase + r * 128 + c0;
    #pragma unroll
    for (int z8 = 0; z8 < 4; ++z8) {
      float4 u0 = *(const float4*)(src + z8 * 8);
      float4 u1 = *(const float4*)(src + z8 * 8 + 4);
      float uv[8] = {u0.x,u0.y,u0.z,u0.w,u1.x,u1.y,u1.z,u1.w};
      union { short s[8]; short8 v; } H, L;
      #pragma unroll
      for (int z = 0; z < 8; ++z) split2(uv[z], H.s[z], L.s[z]);
      *(short8*)(bh + r * BHP + c0 + z8 * 8) = H.v;
      *(short8*)(bl + r * BHP + c0 + z8 * 8) = L.v;
    }
  }
  __syncthreads();

  const floatx4 zf = {0.f, 0.f, 0.f, 0.f};
  floatx4 acc[4] = {zf, zf, zf, zf};

  #pragma unroll
  for (int kc = 0; kc < 4; ++kc) {
    const float* xp = x + (long)arow * 128 + kc * 32 + hq * 8;
    float4 a0 = *(const float4*)xp;
    float4 a1 = *(const float4*)(xp + 4);
    union { short s[8]; short8 v; } Ah, Al;
    float av[8] = {a0.x,a0.y,a0.z,a0.w,a1.x,a1.y,a1.z,a1.w};
    #pragma unroll
    for (int z = 0; z < 8; ++z) split2(av[z], Ah.s[z], Al.s[z]);
    #pragma unroll
    for (int ns = 0; ns < 4; ++ns) {
      short8 Bh = *(const short8*)(bh + (ns * 16 + ln) * BHP + kc * 32 + hq * 8);
      short8 Bl = *(const short8*)(bl + (ns * 16 + ln) * BHP + kc * 32 + hq * 8);
      acc[ns] = __builtin_amdgcn_mfma_f32_16x16x32_bf16(Ah.v, Bh, acc[ns], 0,0,0);
      acc[ns] = __builtin_amdgcn_mfma_f32_16x16x32_bf16(Al.v, Bh, acc[ns], 0,0,0);
      acc[ns] = __builtin_amdgcn_mfma_f32_16x16x32_bf16(Ah.v, Bl, acc[ns], 0,0,0);
    }
  }

  if (nt < 2) {
    short* dst = (nt == 0) ? qb : kb;
    #pragma unroll
    for (int ns = 0; ns < 4; ++ns) {
      int col = ns * 16 + ln;
      #pragma unroll
      for (int reg = 0; reg < 4; ++reg) {
        int row = mt * 64 + w * 16 + hq * 4 + reg;
        dst[(long)row * 64 + col] = f2b(acc[ns][reg]);
      }
    }
  } else {
    int b = mt >> 4;
    int tok = (mt * 64 + w * 16 + hq * 4) & 1023;
    #pragma unroll
    for (int ns = 0; ns < 4; ++ns) {
      int cv = (nt - 2) * 64 + ns * 16 + ln;
      union { short s[4]; short4v v; } o;
      #pragma unroll
      for (int reg = 0; reg < 4; ++reg) o.s[reg] = f2b(acc[ns][reg]);
      *(short4v*)(vtb + ((long)b * CC + cv) * NN + tok) = o.v;
    }
  }
}

// ---------------- Kernel B: single-buffer mrec + reg prefetch, SPLIT=2 ----
// grid 1024 (= 4 blocks/CU, fully co-resident at 29184 B LDS): sp = bx&1,
// itile = (bx>>1)&63, b = bx>>7. NO vgpr-cap launch_bounds (r9 lesson:
// (256,5) forced spill-to-scratch -> 550 MB/iter HBM). Per 64-j tile:
// QK->arec + prefetch next masks->regs | bar1 | mix+PV | bar2 | commit regs->mrec.
#define IT 16
#define JT 64
#define SPLIT 2
#define JSPAN 512
#define NTL 8
#define ARP 260   // dwords per i-row of arec: arec[i][j*4+g]
#define MRP 196   // dwords per i-row of mrec: mrec[i][j*3+m]

__global__ __launch_bounds__(256, 3) void attn_kernel(
    const short* __restrict__ qb, const short* __restrict__ kb,
    const short* __restrict__ vtb, const float* __restrict__ masks,
    const float* __restrict__ mask_proj,
    float* __restrict__ pnum, float* __restrict__ pden3)
{
  __shared__ float arec[IT * ARP];   // 16640 B
  __shared__ float mrec[IT * MRP];   // 12544 B   (29184 B -> 5 blocks/CU cap)

  const int t = threadIdx.x;
  const int sp = blockIdx.x & 1;
  const int itile = (blockIdx.x >> 1) & 63;
  const int b = blockIdx.x >> 7;
  const int i0 = itile * IT;

  const int w = t >> 6;          // wave id: g (QK) ; l-pair owner (mix+PV)
  const int lane = t & 63;
  const int ln = lane & 15;
  const int hq = lane >> 4;
  const int l0 = 2 * w, l1 = 2 * w + 1;

  // mask staging geometry: f = t + it2*256 -> (ii = f/48, rem = f%48) float4s
  const float* mgp[3];
  float* mlp[3];
  #pragma unroll
  for (int it2 = 0; it2 < 3; ++it2) {
    int f = t + it2 * 256;
    int ii = f / 48;
    int rem = f - ii * 48;
    mgp[it2] = masks + (long)(i0 + ii) * (NN * 3) + rem * 4;   // + j0*3 later
    mlp[it2] = mrec + ii * MRP + rem * 4;
  }

  // Q A-fragment (g = w), K-dim zero-padded 16->32 (hq>=2 lanes zero)
  short8 qf;
  {
    union { short s[8]; short8 v; } qq;
    #pragma unroll
    for (int z = 0; z < 8; ++z) qq.s[z] = 0;
    if (hq < 2)
      qq.v = *(const short8*)(qb + ((long)(b * NN + i0 + ln)) * GD + w * 16 + hq * 8);
    qf = qq.v;
  }
  // mix constants folded into exp2 domain (lane-uniform -> SGPRs)
  const float LOG2E = 1.44269504088896340736f;
  float ycA[3][4], ycB[3][4];
  #pragma unroll
  for (int m = 0; m < 3; ++m)
    #pragma unroll
    for (int g = 0; g < 4; ++g) {
      ycA[m][g] = mask_proj[m * 32 + g * 8 + l0] * LOG2E;
      ycB[m][g] = mask_proj[m * 32 + g * 8 + l1] * LOG2E;
    }

  const floatx4 zf = {0.f, 0.f, 0.f, 0.f};
  floatx4 pv0 = zf, pv1 = zf;
  float den0 = 0.f, den1 = 0.f;

  const short* kbase = kb + (long)b * NN * GD;
  const short* v0base = vtb + ((long)b * CC + l0 * 16 + ln) * NN;
  const short* v1base = vtb + ((long)b * CC + l1 * 16 + ln) * NN;

  const int jb0 = sp * JSPAN;
  float4 mpre[3];

  // prologue: stage tile 0 masks (bar1 of iter 0 makes it visible)
  #pragma unroll
  for (int it2 = 0; it2 < 3; ++it2)
    mpre[it2] = *(const float4*)(mgp[it2] + (long)jb0 * 3);
  #pragma unroll
  for (int it2 = 0; it2 < 3; ++it2)
    *(float4*)(mlp[it2]) = mpre[it2];

  for (int jt = 0; jt < NTL; ++jt) {
    const int j0 = jb0 + jt * JT;

    // ---- QK: wave g = w, K direct from global -> arec[i][j*4+g] ----
    #pragma unroll
    for (int jsub = 0; jsub < 4; ++jsub) {
      union { short s[8]; short8 v; } kk;
      #pragma unroll
      for (int z = 0; z < 8; ++z) kk.s[z] = 0;
      if (hq < 2)
        kk.v = *(const short8*)(kbase + (long)(j0 + jsub * 16 + ln) * GD + w * 16 + hq * 8);
      floatx4 at = __builtin_amdgcn_mfma_f32_16x16x32_bf16(qf, kk.v, zf, 0, 0, 0);
      float* ab = arec + (jsub * 16 + ln) * 4 + w;
      #pragma unroll
      for (int reg = 0; reg < 4; ++reg)
        ab[(hq * 4 + reg) * ARP] = at[reg];
    }

    // ---- prefetch next tile's masks into registers (overlaps bar1+mix) ----
    {
      const long jn3 = (long)(jt + 1 < NTL ? j0 + JT : j0) * 3;
      #pragma unroll
      for (int it2 = 0; it2 < 3; ++it2)
        mpre[it2] = *(const float4*)(mgp[it2] + jn3);
    }
    __syncthreads();   // bar1: arec + mrec(jt) ready

    // ---- mix + exp2 + PV: thread = (i=ln, j-octet=hq), l = 2w, 2w+1 ----
    #pragma unroll
    for (int mf = 0; mf < 2; ++mf) {
      float mku[24];
      {
        const float* mb = mrec + ln * MRP + mf * 96 + hq * 24;
        #pragma unroll
        for (int q4 = 0; q4 < 6; ++q4)
          *(float4*)(mku + q4 * 4) = *(const float4*)(mb + q4 * 4);
      }
      short8 vf0 = *(const short8*)(v0base + j0 + mf * 32 + hq * 8);
      short8 vf1 = *(const short8*)(v1base + j0 + mf * 32 + hq * 8);
      const float* arA = arec + ln * ARP + (mf * 32 + hq * 8) * 4;
      union { unsigned u[4]; short8 v; } p0, p1;
      #pragma unroll
      for (int zp = 0; zp < 4; ++zp) {
        float eA[2], eB[2];
        #pragma unroll
        for (int zz = 0; zz < 2; ++zz) {
          int z = zp * 2 + zz;
          floatx4 a4 = *(const floatx4*)(arA + z * 4);
          float m0 = mku[z * 3], m1 = mku[z * 3 + 1], m2 = mku[z * 3 + 2];
          float wA0 = m0*ycA[0][0] + m1*ycA[1][0] + m2*ycA[2][0];
          float wA1 = m0*ycA[0][1] + m1*ycA[1][1] + m2*ycA[2][1];
          float wA2 = m0*ycA[0][2] + m1*ycA[1][2] + m2*ycA[2][2];
          float wA3 = m0*ycA[0][3] + m1*ycA[1][3] + m2*ycA[2][3];
          float wB0 = m0*ycB[0][0] + m1*ycB[1][0] + m2*ycB[2][0];
          float wB1 = m0*ycB[0][1] + m1*ycB[1][1] + m2*ycB[2][1];
          float wB2 = m0*ycB[0][2] + m1*ycB[1][2] + m2*ycB[2][2];
          float wB3 = m0*ycB[0][3] + m1*ycB[1][3] + m2*ycB[2][3];
          float sA = a4[0]*wA0 + a4[1]*wA1 + a4[2]*wA2 + a4[3]*wA3;
          float sB = a4[0]*wB0 + a4[1]*wB1 + a4[2]*wB2 + a4[3]*wB3;
          eA[zz] = EXP2(sA);
          eB[zz] = EXP2(sB);
        }
        den0 += eA[0] + eA[1];
        den1 += eB[0] + eB[1];
        p0.u[zp] = pk2(eA[0], eA[1]);
        p1.u[zp] = pk2(eB[0], eB[1]);
      }
      pv0 = __builtin_amdgcn_mfma_f32_16x16x32_bf16(p0.v, vf0, pv0, 0, 0, 0);
      pv1 = __builtin_amdgcn_mfma_f32_16x16x32_bf16(p1.v, vf1, pv1, 0, 0, 0);
    }
    __syncthreads();   // bar2: mix reads of mrec/arec done

    // ---- commit prefetched masks -> mrec (visible at next bar1) ----
    #pragma unroll
    for (int it2 = 0; it2 < 3; ++it2)
      *(float4*)(mlp[it2]) = mpre[it2];
  }

  // ---- epilogue: partial numerators + per-hq partial denominators ----
  #pragma unroll
  for (int reg = 0; reg < 4; ++reg) {
    long row = ((long)(sp * BB + b)) * NN + i0 + hq * 4 + reg;
    pnum[row * CC + l0 * 16 + ln] = pv0[reg];
    pnum[row * CC + l1 * 16 + ln] = pv1[reg];
  }
  long drow = ((long)(sp * BB + b)) * NN + i0 + ln;
  pden3[drow * 32 + l0 * 4 + hq] = den0;
  pden3[drow * 32 + l1 * 4 + hq] = den1;
}

// ---------------- Kernel C: combine partials ----------------
__global__ __launch_bounds__(256) void reduce_kernel(
    const float* __restrict__ pnum, const float* __restrict__ pden3,
    float* __restrict__ out)
{
  int e4 = blockIdx.x * 256 + threadIdx.x;   // float4 index
  int bi = e4 >> 5;                          // token 0..8191
  int l = (e4 & 31) >> 2;
  const float4* p4 = (const float4*)pnum;
  float4 n = {0.f, 0.f, 0.f, 0.f};
  float den = 0.f;
  #pragma unroll
  for (int s = 0; s < SPLIT; ++s) {
    float4 ns = p4[e4 + (long)s * (BB * NN * CC / 4)];
    n.x += ns.x; n.y += ns.y; n.z += ns.z; n.w += ns.w;
    float4 d4 = *(const float4*)(pden3 + ((long)s * BB * NN + bi) * 32 + l * 4);
    den += d4.x + d4.y + d4.z + d4.w;
  }
  float inv = 1.0f / den;
  float4 o;
  o.x = n.x * inv; o.y = n.y * inv; o.z = n.z * inv; o.w = n.w * inv;
  ((float4*)out)[e4] = o;
}

extern "C" void kernel_launch(void* const* d_in, const int* in_sizes, int n_in,
                              void* d_out, int out_size, void* d_ws, size_t ws_size,
                              hipStream_t stream) {
  const float* x         = (const float*)d_in[0];
  const float* masks     = (const float*)d_in[1];
  const float* Wq        = (const float*)d_in[2];
  const float* Wk        = (const float*)d_in[3];
  const float* Wv        = (const float*)d_in[4];
  const float* mask_proj = (const float*)d_in[5];
  float* out = (float*)d_out;

  // ws bytes: qb 1M | kb 1M | vtb 2M | pnum 8M | pden3 2M = 14 MB
  char* wsB = (char*)d_ws;
  short* qb    = (short*)(wsB);
  short* kb    = (short*)(wsB + (1l << 20));
  short* vtb   = (short*)(wsB + (2l << 20));
  float* pnum  = (float*)(wsB + (4l << 20));
  float* pden3 = (float*)(wsB + (12l << 20));

  proj_kernel<<<512, 256, 0, stream>>>(x, Wq, Wk, Wv, qb, kb, vtb);
  attn_kernel<<<BB * (NN / IT) * SPLIT, 256, 0, stream>>>(qb, kb, vtb, masks,
                                                          mask_proj, pnum, pden3);
  reduce_kernel<<<(BB * NN * CC / 4) / 256, 256, 0, stream>>>(pnum, pden3, out);
}

// Round 12
// 132.282 us; speedup vs baseline: 1.0888x; 1.0888x over previous
//
#include <hip/hip_runtime.h>

#define BB 8
#define NN 1024
#define CC 128
#define GG 4
#define LL 8
#define GD 64

typedef __attribute__((ext_vector_type(8))) short short8;
typedef __attribute__((ext_vector_type(4))) short short4v;
typedef __attribute__((ext_vector_type(4))) float floatx4;

__device__ __forceinline__ short f2b(float f) {
  union { float f; unsigned u; } c; c.f = f;
  unsigned u = c.u;
  return (short)((u + 0x7FFFu + ((u >> 16) & 1u)) >> 16);   // RNE fp32->bf16
}
__device__ __forceinline__ float b2f(short s) {
  union { unsigned u; float f; } c; c.u = ((unsigned)(unsigned short)s) << 16;
  return c.f;
}
__device__ __forceinline__ void split2(float v, short& hi, short& lo) {
  short h = f2b(v);
  hi = h;
  lo = f2b(v - b2f(h));
}

// packed fp32x2 -> bf16x2 (dword: low=a, high=b)
#if __has_builtin(__builtin_amdgcn_cvt_pk_bf16_f32)
__device__ __forceinline__ unsigned pk2(float a, float b) {
  auto r = __builtin_amdgcn_cvt_pk_bf16_f32(a, b);
  unsigned u; __builtin_memcpy(&u, &r, 4); return u;
}
#else
__device__ __forceinline__ unsigned pk2(float a, float b) {
  return (unsigned)(unsigned short)f2b(a) | ((unsigned)(unsigned short)f2b(b) << 16);
}
#endif

#if __has_builtin(__builtin_amdgcn_exp2f)
#define EXP2(x) __builtin_amdgcn_exp2f(x)
#else
#define EXP2(x) exp2f(x)
#endif

// ---------------- Kernel A: projections, W hi/lo-split staged in LDS ------
#define BHP 136   // shorts per W row in LDS; 68 dwords, 68%32=4 -> 2-way free

__global__ __launch_bounds__(256) void proj_kernel(
    const float* __restrict__ x, const float* __restrict__ Wq,
    const float* __restrict__ Wk, const float* __restrict__ Wv,
    short* __restrict__ qb, short* __restrict__ kb, short* __restrict__ vtb)
{
  __shared__ short bh[64 * BHP];   // 17408 B
  __shared__ short bl[64 * BHP];   // 17408 B
  const int t = threadIdx.x;
  const int nt = blockIdx.x & 3;
  const int mt = blockIdx.x >> 2;
  const int w = t >> 6;
  const int lane = t & 63;
  const int ln = lane & 15;
  const int hq = lane >> 4;
  const int arow = mt * 64 + w * 16 + ln;

  const float* wbase = (nt == 0) ? Wq : (nt == 1) ? Wk : (Wv + (nt - 2) * 64 * 128);

  // stage + split W: thread -> row t>>2, cols (t&3)*32..+31
  {
    int r = t >> 2, c0 = (t & 3) * 32;
    const float* src = wbase + r * 128 + c0;
    #pragma unroll
    for (int z8 = 0; z8 < 4; ++z8) {
      float4 u0 = *(const float4*)(src + z8 * 8);
      float4 u1 = *(const float4*)(src + z8 * 8 + 4);
      float uv[8] = {u0.x,u0.y,u0.z,u0.w,u1.x,u1.y,u1.z,u1.w};
      union { short s[8]; short8 v; } H, L;
      #pragma unroll
      for (int z = 0; z < 8; ++z) split2(uv[z], H.s[z], L.s[z]);
      *(short8*)(bh + r * BHP + c0 + z8 * 8) = H.v;
      *(short8*)(bl + r * BHP + c0 + z8 * 8) = L.v;
    }
  }
  __syncthreads();

  const floatx4 zf = {0.f, 0.f, 0.f, 0.f};
  floatx4 acc[4] = {zf, zf, zf, zf};

  #pragma unroll
  for (int kc = 0; kc < 4; ++kc) {
    const float* xp = x + (long)arow * 128 + kc * 32 + hq * 8;
    float4 a0 = *(const float4*)xp;
    float4 a1 = *(const float4*)(xp + 4);
    union { short s[8]; short8 v; } Ah, Al;
    float av[8] = {a0.x,a0.y,a0.z,a0.w,a1.x,a1.y,a1.z,a1.w};
    #pragma unroll
    for (int z = 0; z < 8; ++z) split2(av[z], Ah.s[z], Al.s[z]);
    #pragma unroll
    for (int ns = 0; ns < 4; ++ns) {
      short8 Bh = *(const short8*)(bh + (ns * 16 + ln) * BHP + kc * 32 + hq * 8);
      short8 Bl = *(const short8*)(bl + (ns * 16 + ln) * BHP + kc * 32 + hq * 8);
      acc[ns] = __builtin_amdgcn_mfma_f32_16x16x32_bf16(Ah.v, Bh, acc[ns], 0,0,0);
      acc[ns] = __builtin_amdgcn_mfma_f32_16x16x32_bf16(Al.v, Bh, acc[ns], 0,0,0);
      acc[ns] = __builtin_amdgcn_mfma_f32_16x16x32_bf16(Ah.v, Bl, acc[ns], 0,0,0);
    }
  }

  if (nt < 2) {
    short* dst = (nt == 0) ? qb : kb;
    #pragma unroll
    for (int ns = 0; ns < 4; ++ns) {
      int col = ns * 16 + ln;
      #pragma unroll
      for (int reg = 0; reg < 4; ++reg) {
        int row = mt * 64 + w * 16 + hq * 4 + reg;
        dst[(long)row * 64 + col] = f2b(acc[ns][reg]);
      }
    }
  } else {
    int b = mt >> 4;
    int tok = (mt * 64 + w * 16 + hq * 4) & 1023;
    #pragma unroll
    for (int ns = 0; ns < 4; ++ns) {
      int cv = (nt - 2) * 64 + ns * 16 + ln;
      union { short s[4]; short4v v; } o;
      #pragma unroll
      for (int reg = 0; reg < 4; ++reg) o.s[reg] = f2b(acc[ns][reg]);
      *(short4v*)(vtb + ((long)b * CC + cv) * NN + tok) = o.v;
    }
  }
}

// ---------------- Kernel B: single mrec, reordered phases, 2 barriers ------
// grid 2048: sp = bx&3, itile = (bx>>2)&63, b = bx>>8. r10 numerics exactly.
// Per 64-j tile: barA (prev mix readers done) | stage masks->mrec + QK->arec
// (disjoint LDS writes, one phase) | barB | mix+PV.  No double buffer, no
// register prefetch (r9/r11: prefetch state spills to scratch). LDS 29184 B
// -> 5 blocks/CU.
#define IT 16
#define JT 64
#define SPLIT 4
#define JSPAN 256
#define NTL 4
#define ARP 260   // dwords per i-row of arec: arec[i][j*4+g]
#define MRP 196   // dwords per i-row of mrec: mrec[i][j*3+m]

__global__ __launch_bounds__(256, 3) void attn_kernel(
    const short* __restrict__ qb, const short* __restrict__ kb,
    const short* __restrict__ vtb, const float* __restrict__ masks,
    const float* __restrict__ mask_proj,
    float* __restrict__ pnum, float* __restrict__ pden3)
{
  __shared__ float arec[IT * ARP];   // 16640 B
  __shared__ float mrec[IT * MRP];   // 12544 B   (29184 B total)

  const int t = threadIdx.x;
  const int sp = blockIdx.x & 3;
  const int itile = (blockIdx.x >> 2) & 63;
  const int b = blockIdx.x >> 8;
  const int i0 = itile * IT;

  const int w = t >> 6;          // wave id: g (QK) ; l-pair owner (mix+PV)
  const int lane = t & 63;
  const int ln = lane & 15;
  const int hq = lane >> 4;
  const int l0 = 2 * w, l1 = 2 * w + 1;

  // Q A-fragment (g = w), K-dim zero-padded 16->32 (hq>=2 lanes zero)
  short8 qf;
  {
    union { short s[8]; short8 v; } qq;
    #pragma unroll
    for (int z = 0; z < 8; ++z) qq.s[z] = 0;
    if (hq < 2)
      qq.v = *(const short8*)(qb + ((long)(b * NN + i0 + ln)) * GD + w * 16 + hq * 8);
    qf = qq.v;
  }
  // mix constants folded into exp2 domain
  const float LOG2E = 1.44269504088896340736f;
  float ycA[3][4], ycB[3][4];
  #pragma unroll
  for (int m = 0; m < 3; ++m)
    #pragma unroll
    for (int g = 0; g < 4; ++g) {
      ycA[m][g] = mask_proj[m * 32 + g * 8 + l0] * LOG2E;
      ycB[m][g] = mask_proj[m * 32 + g * 8 + l1] * LOG2E;
    }

  const floatx4 zf = {0.f, 0.f, 0.f, 0.f};
  floatx4 pv0 = zf, pv1 = zf;
  float den0 = 0.f, den1 = 0.f;

  const short* kbase = kb + (long)b * NN * GD;
  const short* v0base = vtb + ((long)b * CC + l0 * 16 + ln) * NN;
  const short* v1base = vtb + ((long)b * CC + l1 * 16 + ln) * NN;

  for (int jt = 0; jt < NTL; ++jt) {
    const int j0 = sp * JSPAN + jt * JT;
    __syncthreads();   // barA: prev tile's mix readers of mrec/arec done

    // ---- stage masks 16i x 64j x 3 (768 float4, coalesced) ----
    #pragma unroll
    for (int it2 = 0; it2 < 3; ++it2) {
      int f = t + it2 * 256;
      int ii = f / 48;
      int rem = f - ii * 48;
      *(float4*)(mrec + ii * MRP + rem * 4) =
        *(const float4*)(masks + (long)(i0 + ii) * (NN * 3) + (long)j0 * 3 + rem * 4);
    }
    // ---- QK: wave g = w, K direct from global (same write-phase) ----
    #pragma unroll
    for (int jsub = 0; jsub < 4; ++jsub) {
      union { short s[8]; short8 v; } kk;
      #pragma unroll
      for (int z = 0; z < 8; ++z) kk.s[z] = 0;
      if (hq < 2)
        kk.v = *(const short8*)(kbase + (long)(j0 + jsub * 16 + ln) * GD + w * 16 + hq * 8);
      floatx4 at = __builtin_amdgcn_mfma_f32_16x16x32_bf16(qf, kk.v, zf, 0, 0, 0);
      float* ab = arec + (jsub * 16 + ln) * 4 + w;     // arec[i][j*4+g]
      #pragma unroll
      for (int reg = 0; reg < 4; ++reg)
        ab[(hq * 4 + reg) * ARP] = at[reg];
    }
    __syncthreads();   // barB: mrec + arec ready

    // ---- mix + exp2 + PV: thread = (i=ln, j-octet=hq), l = 2w, 2w+1 ----
    #pragma unroll
    for (int mf = 0; mf < 2; ++mf) {
      float mku[24];
      {
        const float* mb = mrec + ln * MRP + mf * 96 + hq * 24;
        #pragma unroll
        for (int q4 = 0; q4 < 6; ++q4)
          *(float4*)(mku + q4 * 4) = *(const float4*)(mb + q4 * 4);
      }
      short8 vf0 = *(const short8*)(v0base + j0 + mf * 32 + hq * 8);
      short8 vf1 = *(const short8*)(v1base + j0 + mf * 32 + hq * 8);
      const float* arA = arec + ln * ARP + (mf * 32 + hq * 8) * 4;
      union { unsigned u[4]; short8 v; } p0, p1;
      #pragma unroll
      for (int zp = 0; zp < 4; ++zp) {
        float eA[2], eB[2];
        #pragma unroll
        for (int zz = 0; zz < 2; ++zz) {
          int z = zp * 2 + zz;
          floatx4 a4 = *(const floatx4*)(arA + z * 4);
          float m0 = mku[z * 3], m1 = mku[z * 3 + 1], m2 = mku[z * 3 + 2];
          float wA0 = m0*ycA[0][0] + m1*ycA[1][0] + m2*ycA[2][0];
          float wA1 = m0*ycA[0][1] + m1*ycA[1][1] + m2*ycA[2][1];
          float wA2 = m0*ycA[0][2] + m1*ycA[1][2] + m2*ycA[2][2];
          float wA3 = m0*ycA[0][3] + m1*ycA[1][3] + m2*ycA[2][3];
          float wB0 = m0*ycB[0][0] + m1*ycB[1][0] + m2*ycB[2][0];
          float wB1 = m0*ycB[0][1] + m1*ycB[1][1] + m2*ycB[2][1];
          float wB2 = m0*ycB[0][2] + m1*ycB[1][2] + m2*ycB[2][2];
          float wB3 = m0*ycB[0][3] + m1*ycB[1][3] + m2*ycB[2][3];
          float sA = a4[0]*wA0 + a4[1]*wA1 + a4[2]*wA2 + a4[3]*wA3;
          float sB = a4[0]*wB0 + a4[1]*wB1 + a4[2]*wB2 + a4[3]*wB3;
          eA[zz] = EXP2(sA);
          eB[zz] = EXP2(sB);
        }
        den0 += eA[0] + eA[1];
        den1 += eB[0] + eB[1];
        p0.u[zp] = pk2(eA[0], eA[1]);
        p1.u[zp] = pk2(eB[0], eB[1]);
      }
      pv0 = __builtin_amdgcn_mfma_f32_16x16x32_bf16(p0.v, vf0, pv0, 0, 0, 0);
      pv1 = __builtin_amdgcn_mfma_f32_16x16x32_bf16(p1.v, vf1, pv1, 0, 0, 0);
    }
  }

  // ---- epilogue: partial numerators + per-hq partial denominators ----
  #pragma unroll
  for (int reg = 0; reg < 4; ++reg) {
    long row = ((long)(sp * BB + b)) * NN + i0 + hq * 4 + reg;
    pnum[row * CC + l0 * 16 + ln] = pv0[reg];
    pnum[row * CC + l1 * 16 + ln] = pv1[reg];
  }
  long drow = ((long)(sp * BB + b)) * NN + i0 + ln;
  pden3[drow * 32 + l0 * 4 + hq] = den0;
  pden3[drow * 32 + l1 * 4 + hq] = den1;
}

// ---------------- Kernel C: combine partials ----------------
__global__ __launch_bounds__(256) void reduce_kernel(
    const float* __restrict__ pnum, const float* __restrict__ pden3,
    float* __restrict__ out)
{
  int e4 = blockIdx.x * 256 + threadIdx.x;   // float4 index
  int bi = e4 >> 5;                          // token 0..8191
  int l = (e4 & 31) >> 2;
  const float4* p4 = (const float4*)pnum;
  float4 n = {0.f, 0.f, 0.f, 0.f};
  float den = 0.f;
  #pragma unroll
  for (int s = 0; s < SPLIT; ++s) {
    float4 ns = p4[e4 + (long)s * (BB * NN * CC / 4)];
    n.x += ns.x; n.y += ns.y; n.z += ns.z; n.w += ns.w;
    float4 d4 = *(const float4*)(pden3 + ((long)s * BB * NN + bi) * 32 + l * 4);
    den += d4.x + d4.y + d4.z + d4.w;
  }
  float inv = 1.0f / den;
  float4 o;
  o.x = n.x * inv; o.y = n.y * inv; o.z = n.z * inv; o.w = n.w * inv;
  ((float4*)out)[e4] = o;
}

extern "C" void kernel_launch(void* const* d_in, const int* in_sizes, int n_in,
                              void* d_out, int out_size, void* d_ws, size_t ws_size,
                              hipStream_t stream) {
  const float* x         = (const float*)d_in[0];
  const float* masks     = (const float*)d_in[1];
  const float* Wq        = (const float*)d_in[2];
  const float* Wk        = (const float*)d_in[3];
  const float* Wv        = (const float*)d_in[4];
  const float* mask_proj = (const float*)d_in[5];
  float* out = (float*)d_out;

  // ws bytes: qb 1M | kb 1M | vtb 2M | pnum 16M | pden3 4M = 24 MB
  char* wsB = (char*)d_ws;
  short* qb    = (short*)(wsB);
  short* kb    = (short*)(wsB + (1l << 20));
  short* vtb   = (short*)(wsB + (2l << 20));
  float* pnum  = (float*)(wsB + (4l << 20));
  float* pden3 = (float*)(wsB + (20l << 20));

  proj_kernel<<<512, 256, 0, stream>>>(x, Wq, Wk, Wv, qb, kb, vtb);
  attn_kernel<<<BB * (NN / IT) * SPLIT, 256, 0, stream>>>(qb, kb, vtb, masks,
                                                          mask_proj, pnum, pden3);
  reduce_kernel<<<(BB * NN * CC / 4) / 256, 256, 0, stream>>>(pnum, pden3, out);
}

// Round 13
// 126.539 us; speedup vs baseline: 1.1382x; 1.0454x over previous
//
#include <hip/hip_runtime.h>

#define BB 8
#define NN 1024
#define CC 128
#define GG 4
#define LL 8
#define GD 64

typedef __attribute__((ext_vector_type(8))) short short8;
typedef __attribute__((ext_vector_type(4))) short short4v;
typedef __attribute__((ext_vector_type(4))) float floatx4;

__device__ __forceinline__ short f2b(float f) {
  union { float f; unsigned u; } c; c.f = f;
  unsigned u = c.u;
  return (short)((u + 0x7FFFu + ((u >> 16) & 1u)) >> 16);   // RNE fp32->bf16
}
__device__ __forceinline__ float b2f(short s) {
  union { unsigned u; float f; } c; c.u = ((unsigned)(unsigned short)s) << 16;
  return c.f;
}
__device__ __forceinline__ void split2(float v, short& hi, short& lo) {
  short h = f2b(v);
  hi = h;
  lo = f2b(v - b2f(h));
}

// packed fp32x2 -> bf16x2 (dword: low=a, high=b)
#if __has_builtin(__builtin_amdgcn_cvt_pk_bf16_f32)
__device__ __forceinline__ unsigned pk2(float a, float b) {
  auto r = __builtin_amdgcn_cvt_pk_bf16_f32(a, b);
  unsigned u; __builtin_memcpy(&u, &r, 4); return u;
}
#else
__device__ __forceinline__ unsigned pk2(float a, float b) {
  return (unsigned)(unsigned short)f2b(a) | ((unsigned)(unsigned short)f2b(b) << 16);
}
#endif

#if __has_builtin(__builtin_amdgcn_exp2f)
#define EXP2(x) __builtin_amdgcn_exp2f(x)
#else
#define EXP2(x) exp2f(x)
#endif

// ---------------- Kernel A: projections, W hi/lo-split staged in LDS ------
#define BHP 136   // shorts per W row in LDS; 68 dwords, 68%32=4 -> 2-way free

__global__ __launch_bounds__(256) void proj_kernel(
    const float* __restrict__ x, const float* __restrict__ Wq,
    const float* __restrict__ Wk, const float* __restrict__ Wv,
    short* __restrict__ qb, short* __restrict__ kb, short* __restrict__ vtb)
{
  __shared__ short bh[64 * BHP];   // 17408 B
  __shared__ short bl[64 * BHP];   // 17408 B
  const int t = threadIdx.x;
  const int nt = blockIdx.x & 3;
  const int mt = blockIdx.x >> 2;
  const int w = t >> 6;
  const int lane = t & 63;
  const int ln = lane & 15;
  const int hq = lane >> 4;
  const int arow = mt * 64 + w * 16 + ln;

  const float* wbase = (nt == 0) ? Wq : (nt == 1) ? Wk : (Wv + (nt - 2) * 64 * 128);

  // stage + split W: thread -> row t>>2, cols (t&3)*32..+31
  {
    int r = t >> 2, c0 = (t & 3) * 32;
    const float* src = wbase + r * 128 + c0;
    #pragma unroll
    for (int z8 = 0; z8 < 4; ++z8) {
      float4 u0 = *(const float4*)(src + z8 * 8);
      float4 u1 = *(const float4*)(src + z8 * 8 + 4);
      float uv[8] = {u0.x,u0.y,u0.z,u0.w,u1.x,u1.y,u1.z,u1.w};
      union { short s[8]; short8 v; } H, L;
      #pragma unroll
      for (int z = 0; z < 8; ++z) split2(uv[z], H.s[z], L.s[z]);
      *(short8*)(bh + r * BHP + c0 + z8 * 8) = H.v;
      *(short8*)(bl + r * BHP + c0 + z8 * 8) = L.v;
    }
  }
  __syncthreads();

  const floatx4 zf = {0.f, 0.f, 0.f, 0.f};
  floatx4 acc[4] = {zf, zf, zf, zf};

  #pragma unroll
  for (int kc = 0; kc < 4; ++kc) {
    const float* xp = x + (long)arow * 128 + kc * 32 + hq * 8;
    float4 a0 = *(const float4*)xp;
    float4 a1 = *(const float4*)(xp + 4);
    union { short s[8]; short8 v; } Ah, Al;
    float av[8] = {a0.x,a0.y,a0.z,a0.w,a1.x,a1.y,a1.z,a1.w};
    #pragma unroll
    for (int z = 0; z < 8; ++z) split2(av[z], Ah.s[z], Al.s[z]);
    #pragma unroll
    for (int ns = 0; ns < 4; ++ns) {
      short8 Bh = *(const short8*)(bh + (ns * 16 + ln) * BHP + kc * 32 + hq * 8);
      short8 Bl = *(const short8*)(bl + (ns * 16 + ln) * BHP + kc * 32 + hq * 8);
      acc[ns] = __builtin_amdgcn_mfma_f32_16x16x32_bf16(Ah.v, Bh, acc[ns], 0,0,0);
      acc[ns] = __builtin_amdgcn_mfma_f32_16x16x32_bf16(Al.v, Bh, acc[ns], 0,0,0);
      acc[ns] = __builtin_amdgcn_mfma_f32_16x16x32_bf16(Ah.v, Bl, acc[ns], 0,0,0);
    }
  }

  if (nt < 2) {
    short* dst = (nt == 0) ? qb : kb;
    #pragma unroll
    for (int ns = 0; ns < 4; ++ns) {
      int col = ns * 16 + ln;
      #pragma unroll
      for (int reg = 0; reg < 4; ++reg) {
        int row = mt * 64 + w * 16 + hq * 4 + reg;
        dst[(long)row * 64 + col] = f2b(acc[ns][reg]);
      }
    }
  } else {
    int b = mt >> 4;
    int tok = (mt * 64 + w * 16 + hq * 4) & 1023;
    #pragma unroll
    for (int ns = 0; ns < 4; ++ns) {
      int cv = (nt - 2) * 64 + ns * 16 + ln;
      union { short s[4]; short4v v; } o;
      #pragma unroll
      for (int reg = 0; reg < 4; ++reg) o.s[reg] = f2b(acc[ns][reg]);
      *(short4v*)(vtb + ((long)b * CC + cv) * NN + tok) = o.v;
    }
  }
}

// ---------------- Kernel B: r12 hot loop, SPLIT=2, shuffle-reduced den ------
// grid 1024 (= exactly 4 blocks/CU, fully co-resident at 29184 B LDS):
// sp = bx&1, itile = (bx>>1)&63, b = bx>>7.
// Per 64-j tile: barA | stage masks->mrec + QK->arec | barB | mix+PV.
#define IT 16
#define JT 64
#define SPLIT 2
#define JSPAN 512
#define NTL 8
#define ARP 260   // dwords per i-row of arec: arec[i][j*4+g]
#define MRP 196   // dwords per i-row of mrec: mrec[i][j*3+m]

__global__ __launch_bounds__(256, 3) void attn_kernel(
    const short* __restrict__ qb, const short* __restrict__ kb,
    const short* __restrict__ vtb, const float* __restrict__ masks,
    const float* __restrict__ mask_proj,
    float* __restrict__ pnum, float* __restrict__ pden)
{
  __shared__ float arec[IT * ARP];   // 16640 B
  __shared__ float mrec[IT * MRP];   // 12544 B   (29184 B total)

  const int t = threadIdx.x;
  const int sp = blockIdx.x & 1;
  const int itile = (blockIdx.x >> 1) & 63;
  const int b = blockIdx.x >> 7;
  const int i0 = itile * IT;

  const int w = t >> 6;          // wave id: g (QK) ; l-pair owner (mix+PV)
  const int lane = t & 63;
  const int ln = lane & 15;
  const int hq = lane >> 4;
  const int l0 = 2 * w, l1 = 2 * w + 1;

  // Q A-fragment (g = w), K-dim zero-padded 16->32 (hq>=2 lanes zero)
  short8 qf;
  {
    union { short s[8]; short8 v; } qq;
    #pragma unroll
    for (int z = 0; z < 8; ++z) qq.s[z] = 0;
    if (hq < 2)
      qq.v = *(const short8*)(qb + ((long)(b * NN + i0 + ln)) * GD + w * 16 + hq * 8);
    qf = qq.v;
  }
  // mix constants folded into exp2 domain
  const float LOG2E = 1.44269504088896340736f;
  float ycA[3][4], ycB[3][4];
  #pragma unroll
  for (int m = 0; m < 3; ++m)
    #pragma unroll
    for (int g = 0; g < 4; ++g) {
      ycA[m][g] = mask_proj[m * 32 + g * 8 + l0] * LOG2E;
      ycB[m][g] = mask_proj[m * 32 + g * 8 + l1] * LOG2E;
    }

  const floatx4 zf = {0.f, 0.f, 0.f, 0.f};
  floatx4 pv0 = zf, pv1 = zf;
  float den0 = 0.f, den1 = 0.f;

  const short* kbase = kb + (long)b * NN * GD;
  const short* v0base = vtb + ((long)b * CC + l0 * 16 + ln) * NN;
  const short* v1base = vtb + ((long)b * CC + l1 * 16 + ln) * NN;

  for (int jt = 0; jt < NTL; ++jt) {
    const int j0 = sp * JSPAN + jt * JT;
    __syncthreads();   // barA: prev tile's mix readers of mrec/arec done

    // ---- stage masks 16i x 64j x 3 (768 float4, coalesced) ----
    #pragma unroll
    for (int it2 = 0; it2 < 3; ++it2) {
      int f = t + it2 * 256;
      int ii = f / 48;
      int rem = f - ii * 48;
      *(float4*)(mrec + ii * MRP + rem * 4) =
        *(const float4*)(masks + (long)(i0 + ii) * (NN * 3) + (long)j0 * 3 + rem * 4);
    }
    // ---- QK: wave g = w, K direct from global (same write-phase) ----
    #pragma unroll
    for (int jsub = 0; jsub < 4; ++jsub) {
      union { short s[8]; short8 v; } kk;
      #pragma unroll
      for (int z = 0; z < 8; ++z) kk.s[z] = 0;
      if (hq < 2)
        kk.v = *(const short8*)(kbase + (long)(j0 + jsub * 16 + ln) * GD + w * 16 + hq * 8);
      floatx4 at = __builtin_amdgcn_mfma_f32_16x16x32_bf16(qf, kk.v, zf, 0, 0, 0);
      float* ab = arec + (jsub * 16 + ln) * 4 + w;     // arec[i][j*4+g]
      #pragma unroll
      for (int reg = 0; reg < 4; ++reg)
        ab[(hq * 4 + reg) * ARP] = at[reg];
    }
    __syncthreads();   // barB: mrec + arec ready

    // ---- mix + exp2 + PV: thread = (i=ln, j-octet=hq), l = 2w, 2w+1 ----
    #pragma unroll
    for (int mf = 0; mf < 2; ++mf) {
      float mku[24];
      {
        const float* mb = mrec + ln * MRP + mf * 96 + hq * 24;
        #pragma unroll
        for (int q4 = 0; q4 < 6; ++q4)
          *(float4*)(mku + q4 * 4) = *(const float4*)(mb + q4 * 4);
      }
      short8 vf0 = *(const short8*)(v0base + j0 + mf * 32 + hq * 8);
      short8 vf1 = *(const short8*)(v1base + j0 + mf * 32 + hq * 8);
      const float* arA = arec + ln * ARP + (mf * 32 + hq * 8) * 4;
      union { unsigned u[4]; short8 v; } p0, p1;
      #pragma unroll
      for (int zp = 0; zp < 4; ++zp) {
        float eA[2], eB[2];
        #pragma unroll
        for (int zz = 0; zz < 2; ++zz) {
          int z = zp * 2 + zz;
          floatx4 a4 = *(const floatx4*)(arA + z * 4);
          float m0 = mku[z * 3], m1 = mku[z * 3 + 1], m2 = mku[z * 3 + 2];
          float wA0 = m0*ycA[0][0] + m1*ycA[1][0] + m2*ycA[2][0];
          float wA1 = m0*ycA[0][1] + m1*ycA[1][1] + m2*ycA[2][1];
          float wA2 = m0*ycA[0][2] + m1*ycA[1][2] + m2*ycA[2][2];
          float wA3 = m0*ycA[0][3] + m1*ycA[1][3] + m2*ycA[2][3];
          float wB0 = m0*ycB[0][0] + m1*ycB[1][0] + m2*ycB[2][0];
          float wB1 = m0*ycB[0][1] + m1*ycB[1][1] + m2*ycB[2][1];
          float wB2 = m0*ycB[0][2] + m1*ycB[1][2] + m2*ycB[2][2];
          float wB3 = m0*ycB[0][3] + m1*ycB[1][3] + m2*ycB[2][3];
          float sA = a4[0]*wA0 + a4[1]*wA1 + a4[2]*wA2 + a4[3]*wA3;
          float sB = a4[0]*wB0 + a4[1]*wB1 + a4[2]*wB2 + a4[3]*wB3;
          eA[zz] = EXP2(sA);
          eB[zz] = EXP2(sB);
        }
        den0 += eA[0] + eA[1];
        den1 += eB[0] + eB[1];
        p0.u[zp] = pk2(eA[0], eA[1]);
        p1.u[zp] = pk2(eB[0], eB[1]);
      }
      pv0 = __builtin_amdgcn_mfma_f32_16x16x32_bf16(p0.v, vf0, pv0, 0, 0, 0);
      pv1 = __builtin_amdgcn_mfma_f32_16x16x32_bf16(p1.v, vf1, pv1, 0, 0, 0);
    }
  }

  // ---- epilogue: partial numerators; den reduced over hq via shuffles ----
  #pragma unroll
  for (int reg = 0; reg < 4; ++reg) {
    long row = ((long)(sp * BB + b)) * NN + i0 + hq * 4 + reg;
    pnum[row * CC + l0 * 16 + ln] = pv0[reg];
    pnum[row * CC + l1 * 16 + ln] = pv1[reg];
  }
  // sum den over the 4 hq lanes (stride-16 within the wave)
  den0 += __shfl_xor(den0, 16, 64);
  den0 += __shfl_xor(den0, 32, 64);
  den1 += __shfl_xor(den1, 16, 64);
  den1 += __shfl_xor(den1, 32, 64);
  if (hq == 0) {
    long drow = ((long)(sp * BB + b)) * NN + i0 + ln;
    pden[drow * LL + l0] = den0;
    pden[drow * LL + l1] = den1;
  }
}

// ---------------- Kernel C: combine partials ----------------
__global__ __launch_bounds__(256) void reduce_kernel(
    const float* __restrict__ pnum, const float* __restrict__ pden,
    float* __restrict__ out)
{
  int e4 = blockIdx.x * 256 + threadIdx.x;   // float4 index
  int bi = e4 >> 5;                          // token 0..8191
  int l = (e4 & 31) >> 2;
  const float4* p4 = (const float4*)pnum;
  float4 n0 = p4[e4];
  float4 n1 = p4[e4 + (BB * NN * CC / 4)];
  float den = pden[(long)bi * LL + l] + pden[((long)BB * NN + bi) * LL + l];
  float inv = 1.0f / den;
  float4 o;
  o.x = (n0.x + n1.x) * inv;
  o.y = (n0.y + n1.y) * inv;
  o.z = (n0.z + n1.z) * inv;
  o.w = (n0.w + n1.w) * inv;
  ((float4*)out)[e4] = o;
}

extern "C" void kernel_launch(void* const* d_in, const int* in_sizes, int n_in,
                              void* d_out, int out_size, void* d_ws, size_t ws_size,
                              hipStream_t stream) {
  const float* x         = (const float*)d_in[0];
  const float* masks     = (const float*)d_in[1];
  const float* Wq        = (const float*)d_in[2];
  const float* Wk        = (const float*)d_in[3];
  const float* Wv        = (const float*)d_in[4];
  const float* mask_proj = (const float*)d_in[5];
  float* out = (float*)d_out;

  // ws bytes: qb 1M | kb 1M | vtb 2M | pnum 8M | pden 0.5M = 12.5 MB
  // (ws poison costs ~1 us/MB per iteration -- keep this small)
  char* wsB = (char*)d_ws;
  short* qb   = (short*)(wsB);
  short* kb   = (short*)(wsB + (1l << 20));
  short* vtb  = (short*)(wsB + (2l << 20));
  float* pnum = (float*)(wsB + (4l << 20));
  float* pden = (float*)(wsB + (12l << 20));

  proj_kernel<<<512, 256, 0, stream>>>(x, Wq, Wk, Wv, qb, kb, vtb);
  attn_kernel<<<BB * (NN / IT) * SPLIT, 256, 0, stream>>>(qb, kb, vtb, masks,
                                                          mask_proj, pnum, pden);
  reduce_kernel<<<(BB * NN * CC / 4) / 256, 256, 0, stream>>>(pnum, pden, out);
}